// Round 14
// baseline (2327.255 us; speedup 1.0000x reference)
//
#include <hip/hip_runtime.h>

typedef unsigned short u16;
typedef __attribute__((ext_vector_type(8))) short s16x8;
typedef __attribute__((ext_vector_type(4))) float f32x4;
typedef __attribute__((ext_vector_type(4))) unsigned short u16x4;

#define DEVI __device__ __forceinline__

DEVI float bf2f(u16 h) { union { unsigned u; float f; } v; v.u = ((unsigned)h) << 16; return v.f; }
DEVI u16 f2bf(float f) {
  union { unsigned u; float f; } v; v.f = f;
  unsigned u = v.u;
  unsigned r = (u + 0x7fffu + ((u >> 16) & 1u)) >> 16;
  return (u16)r;
}

DEVI f32x4 mfma16(s16x8 a, s16x8 b, f32x4 c) {
  return __builtin_amdgcn_mfma_f32_16x16x32_bf16(a, b, c, 0, 0, 0);
}

// ---------------- fused setup: weight repack/cvt + QKV bias + embedding ----------------
DEVI void cvt8(const float* __restrict__ in, u16* __restrict__ out, int i) {
  const f32x4* p = (const f32x4*)(in + (size_t)i * 8);
  f32x4 a = p[0], b = p[1];
  u16x4 o0 = { f2bf(a[0]), f2bf(a[1]), f2bf(a[2]), f2bf(a[3]) };
  u16x4 o1 = { f2bf(b[0]), f2bf(b[1]), f2bf(b[2]), f2bf(b[3]) };
  u16x4* q = (u16x4*)(out + (size_t)i * 8);
  q[0] = o0; q[1] = o1;
}

__global__ void prep_kern(const float* __restrict__ Wq, const float* __restrict__ Wk,
                          const float* __restrict__ Wv, const float* __restrict__ Wo,
                          const float* __restrict__ Wc1, const float* __restrict__ Wc2,
                          const float* __restrict__ bq, const float* __restrict__ bk,
                          const float* __restrict__ bv,
                          const int* __restrict__ tok, const float* __restrict__ emb,
                          u16* __restrict__ Wqkvb, u16* __restrict__ Wob,
                          u16* __restrict__ Wc1b, u16* __restrict__ Wc2b,
                          float* __restrict__ bqkvb, u16* __restrict__ xb) {
  const int Rqkv = 6 * 1536 * 512 / 8;   // 589824
  const int Rwo  = 6 * 512 * 512 / 8;    // 196608
  const int Rw1  = 6 * 2048 * 512 / 8;   // 786432
  const int Rw2  = Rw1;
  const int Rb   = 6 * 1536 / 8;         // 1152
  const int Remb = 8192 * 128;           // 1048576 (4 dims each)
  const int total = Rqkv + Rwo + Rw1 + Rw2 + Rb + Remb;
  for (int idx = blockIdx.x * blockDim.x + threadIdx.x; idx < total;
       idx += gridDim.x * blockDim.x) {
    int i = idx;
    if (i < Rqkv) {
      int c8 = i & 63;
      int t = i >> 6;                    // l*1536 + r
      int r = t % 1536, l = t / 1536;
      const float* src; int rr = r;
      if (r < 512) src = Wq;
      else if (r < 1024) { src = Wk; rr = r - 512; }
      else { src = Wv; rr = r - 1024; }
      const f32x4* p = (const f32x4*)(src + ((size_t)(l * 512 + rr) * 512) + c8 * 8);
      f32x4 a = p[0], b = p[1];
      u16x4 o0 = { f2bf(a[0]), f2bf(a[1]), f2bf(a[2]), f2bf(a[3]) };
      u16x4 o1 = { f2bf(b[0]), f2bf(b[1]), f2bf(b[2]), f2bf(b[3]) };
      u16x4* q = (u16x4*)(Wqkvb + (size_t)i * 8);
      q[0] = o0; q[1] = o1;
      continue;
    }
    i -= Rqkv;
    if (i < Rwo) { cvt8(Wo, Wob, i); continue; }
    i -= Rwo;
    if (i < Rw1) { cvt8(Wc1, Wc1b, i); continue; }
    i -= Rw1;
    if (i < Rw2) { cvt8(Wc2, Wc2b, i); continue; }
    i -= Rw2;
    if (i < Rb) {
      #pragma unroll
      for (int u = 0; u < 8; ++u) {
        int j = i * 8 + u;
        int l = j / 1536, r = j % 1536;
        float v = (r < 512) ? bq[l * 512 + r]
                : (r < 1024) ? bk[l * 512 + r - 512] : bv[l * 512 + r - 1024];
        bqkvb[j] = v;
      }
      continue;
    }
    i -= Rb;
    // embedding + pos enc: item i -> (bs, 4-dim chunk)
    {
      int bs = i >> 7;
      int t = i & 127;
      int s = bs & 511;
      int id = tok[bs];
      float pos = (float)(s + 1);
      int j0 = t * 4;
      f32x4 e = *(const f32x4*)(emb + (size_t)id * 512 + j0);
      u16x4 ob;
      #pragma unroll
      for (int u = 0; u < 4; ++u) {
        int j = j0 + u;
        float expo = (float)(j & ~1) * (1.0f / 512.0f);
        float ang = pos / powf(10000.0f, expo);
        float pe = (j & 1) ? cosf(ang) : sinf(ang);
        ob[u] = f2bf(e[u] + pe);
      }
      *(u16x4*)(xb + (size_t)bs * 512 + j0) = ob;
    }
  }
}

// ---------------- B-stationary MFMA GEMM: C = A[M,K] * Bt[N,K]^T ----------------
template <int WM, bool RELU, bool VT>
__global__ __launch_bounds__(256, 2) void gemm_bs(const u16* __restrict__ A,
                                                  const u16* __restrict__ Bt,
                                                  const float* __restrict__ bias,
                                                  u16* __restrict__ Cb, u16* __restrict__ Vt,
                                                  int N, int K, int nN) {
  constexpr int MF = WM / 16;         // m-frags per wave
  constexpr int RPB = WM * 4;         // rows per block
  __shared__ __align__(16) u16 Bsw[128 * 256];   // 64 KB swizzled panel

  const int chunkw = gridDim.x >> 3;
  const int wgid = (blockIdx.x & 7) * chunkw + (blockIdx.x >> 3);
  const int n = wgid % nN, m = wgid / nN;
  const int bn0 = n * 128, bm0 = m * RPB;

  const int tid = threadIdx.x, lane = tid & 63, wid = tid >> 6;
  const int l15 = lane & 15, lhi = lane >> 4;
  const int mrow0 = bm0 + wid * WM;

  f32x4 acc[MF][8];
  #pragma unroll
  for (int i = 0; i < MF; ++i)
    #pragma unroll
    for (int j = 0; j < 8; ++j)
      #pragma unroll
      for (int r = 0; r < 4; ++r) acc[i][j][r] = 0.0f;

  const u16* aB[MF];
  #pragma unroll
  for (int i = 0; i < MF; ++i)
    aB[i] = A + (size_t)(mrow0 + i * 16 + l15) * K + lhi * 8;

  const int rounds = K >> 8;            // K / 256
  for (int r = 0; r < rounds; ++r) {
    const int kb = r << 8;
    s16x8 tmp[16];
    #pragma unroll
    for (int c = 0; c < 16; ++c) {
      int cc = c * 256 + tid;           // chunk 0..4095 (16B each)
      int row = cc >> 5, col = cc & 31;
      tmp[c] = *(const s16x8*)(Bt + (size_t)(bn0 + row) * K + kb + col * 8);
    }
    __syncthreads();                    // previous panel fully consumed
    #pragma unroll
    for (int c = 0; c < 16; ++c) {
      int cc = c * 256 + tid;
      int row = cc >> 5, col = cc & 31;
      int byte = row * 512 + ((col * 16) ^ ((row & 7) << 4));
      *(s16x8*)((char*)Bsw + byte) = tmp[c];
    }
    __syncthreads();                    // panel ready
    #pragma unroll
    for (int ks = 0; ks < 8; ++ks) {
      s16x8 af[MF], bf[8];
      #pragma unroll
      for (int i = 0; i < MF; ++i)
        af[i] = *(const s16x8*)(aB[i] + kb + ks * 32);
      #pragma unroll
      for (int j = 0; j < 8; ++j) {
        int row = j * 16 + l15;
        int byte = row * 512 + (((ks * 64) + lhi * 16) ^ ((row & 7) << 4));
        bf[j] = *(const s16x8*)((char*)Bsw + byte);
      }
      #pragma unroll
      for (int i = 0; i < MF; ++i)
        #pragma unroll
        for (int j = 0; j < 8; ++j)
          acc[i][j] = mfma16(af[i], bf[j], acc[i][j]);
    }
  }

  const int r0 = mrow0 + lhi * 4;
  const int c0 = bn0 + l15;
  if (VT && bn0 >= 1024) {
    // V columns: repack tile via LDS (Bsw dead) -> transposed coalesced stores
    __syncthreads();                    // all B-frag reads of Bsw done
    u16* T = Bsw;                       // [128 s][136] overlay
    #pragma unroll
    for (int i = 0; i < MF; ++i)
      #pragma unroll
      for (int j = 0; j < 8; ++j) {
        int col = c0 + j * 16;
        float bv = bias[col];
        int lr0 = wid * WM + i * 16 + lhi * 4;      // local s row
        int lc = j * 16 + l15;                      // local d col
        #pragma unroll
        for (int r = 0; r < 4; ++r)
          T[(lr0 + r) * 136 + lc] = f2bf(acc[i][j][r] + bv);
      }
    __syncthreads();
    const int b = bm0 >> 9, s0 = bm0 & 511;
    for (int c = tid; c < 2048; c += 256) {
      int dr = c >> 4;                  // local d col 0..127
      int ch = c & 15;                  // 16 chunks of 8 s
      s16x8 v;
      #pragma unroll
      for (int k = 0; k < 8; ++k) v[k] = T[(ch * 8 + k) * 136 + dr];
      int hc = bn0 - 1024 + dr;
      int h = hc >> 6, d = hc & 63;
      *(s16x8*)&Vt[((size_t)((b * 8 + h) * 64 + d)) * 512 + s0 + ch * 8] = v;
    }
  } else {
    #pragma unroll
    for (int i = 0; i < MF; ++i)
      #pragma unroll
      for (int j = 0; j < 8; ++j) {
        int col = c0 + j * 16;
        float bv = bias[col];
        #pragma unroll
        for (int r = 0; r < 4; ++r) {
          int row = r0 + i * 16 + r;
          float v = acc[i][j][r] + bv;
          if (RELU) v = fmaxf(v, 0.0f);
          Cb[(size_t)row * N + col] = f2bf(v);
        }
      }
  }
}

// ---------------- LN over 512: bf16 pre-act + bf16 resid; writes bf16 (+f32 opt) ----------------
__global__ void ln2_kern(const u16* __restrict__ parts,
                         const u16* __restrict__ resid,
                         const float* __restrict__ gam, const float* __restrict__ bet,
                         float* __restrict__ outf, u16* __restrict__ outb) {
  int row = blockIdx.x * 4 + (threadIdx.x >> 6);
  int t = threadIdx.x & 63;
  size_t base = (size_t)row * 512;
  const u16x4* pp = (const u16x4*)(parts + base);
  u16x4 pa = pp[t], pb4 = pp[t + 64];
  const u16x4* rp = (const u16x4*)(resid + base);
  u16x4 ra = rp[t], rb = rp[t + 64];
  f32x4 v0, v1;
  #pragma unroll
  for (int u = 0; u < 4; ++u) {
    v0[u] = bf2f(pa[u]) + bf2f(ra[u]);
    v1[u] = bf2f(pb4[u]) + bf2f(rb[u]);
  }

  float s = v0[0] + v0[1] + v0[2] + v0[3] + v1[0] + v1[1] + v1[2] + v1[3];
  float q = v0[0]*v0[0] + v0[1]*v0[1] + v0[2]*v0[2] + v0[3]*v0[3]
          + v1[0]*v1[0] + v1[1]*v1[1] + v1[2]*v1[2] + v1[3]*v1[3];
  #pragma unroll
  for (int d = 1; d < 64; d <<= 1) { s += __shfl_xor(s, d, 64); q += __shfl_xor(q, d, 64); }
  float mu = s * (1.0f / 512.0f);
  float var = q * (1.0f / 512.0f) - mu * mu;
  float rs = rsqrtf(var + 1e-5f);
  const f32x4* gp = (const f32x4*)gam;
  const f32x4* bp = (const f32x4*)bet;
  f32x4 ga = gp[t], gb = gp[t + 64], ba = bp[t], bb = bp[t + 64];
  f32x4 o0, o1; u16x4 ob0, ob1;
  #pragma unroll
  for (int u = 0; u < 4; ++u) {
    float a0 = (v0[u] - mu) * rs * ga[u] + ba[u];
    float a1 = (v1[u] - mu) * rs * gb[u] + bb[u];
    o0[u] = a0; o1[u] = a1; ob0[u] = f2bf(a0); ob1[u] = f2bf(a1);
  }
  u16x4* obp = (u16x4*)(outb + base);
  obp[t] = ob0; obp[t + 64] = ob1;
  if (outf) {
    f32x4* op = (f32x4*)(outf + base);
    op[t] = o0; op[t + 64] = o1;
  }
}

// ---------------- fused attention (DIAGNOSTIC: reps re-run entire body) ----------------
__global__ void attn_kern(const u16* __restrict__ QKV, const u16* __restrict__ Vt,
                          const int* __restrict__ tok,
                          float* __restrict__ wout, u16* __restrict__ ctxb, int reps) {
  // bijective XCD chunking (grid=2048): one XCD gets all 16 qt of 16 (b,h) groups
  int wg = (blockIdx.x & 7) * 256 + (blockIdx.x >> 3);
  int qt = wg & 15;          // 16 q-tiles of 32 rows
  int h = (wg >> 4) & 7;
  int b = wg >> 7;
  int tid = threadIdx.x;
  int lane = tid & 63, wid = tid >> 6;
  int l15 = lane & 15, lhi = lane >> 4;
  int m0 = qt * 32;

  __shared__ __align__(16) u16 Wl[32][528];
  __shared__ float pmask[512];
  __shared__ float redbuf[2][32][4];

  for (int rep = 0; rep < reps; ++rep) {
  __syncthreads();           // prior rep's LDS reads done before rewriting

  for (int c = tid; c < 512; c += 256)
    pmask[c] = (tok[b * 512 + c] == 0) ? 1.0f : 0.0f;

  s16x8 qf[2][2];
  const u16* qbase = QKV + (size_t)(b * 512 + m0) * 1536 + h * 64;
  #pragma unroll
  for (int i = 0; i < 2; ++i)
    #pragma unroll
    for (int kk = 0; kk < 2; ++kk)
      qf[i][kk] = *(const s16x8*)(qbase + (size_t)(i * 16 + l15) * 1536 + kk * 32 + lhi * 8);

  f32x4 sacc[2][8];
  #pragma unroll
  for (int i = 0; i < 2; ++i)
    #pragma unroll
    for (int j = 0; j < 8; ++j)
      #pragma unroll
      for (int r = 0; r < 4; ++r) sacc[i][j][r] = 0.0f;

  int c0 = wid * 128;
  const u16* kbase = QKV + (size_t)(b * 512 + c0) * 1536 + 512 + h * 64;
  #pragma unroll
  for (int j = 0; j < 8; ++j) {
    #pragma unroll
    for (int kk = 0; kk < 2; ++kk) {
      s16x8 kf = *(const s16x8*)(kbase + (size_t)(j * 16 + l15) * 1536 + kk * 32 + lhi * 8);
      sacc[0][j] = mfma16(qf[0][kk], kf, sacc[0][j]);
      sacc[1][j] = mfma16(qf[1][kk], kf, sacc[1][j]);
    }
  }
  __syncthreads();  // pmask staged

  float rm[2][4], sm[2][4], gi[2][4];
  #pragma unroll
  for (int i = 0; i < 2; ++i)
    #pragma unroll
    for (int r = 0; r < 4; ++r) rm[i][r] = -3.0e38f;

  #pragma unroll
  for (int j = 0; j < 8; ++j) {
    float pm = pmask[c0 + j * 16 + l15];
    #pragma unroll
    for (int i = 0; i < 2; ++i)
      #pragma unroll
      for (int r = 0; r < 4; ++r) {
        float sv = sacc[i][j][r] * 0.125f;
        sv = (pm != 0.0f) ? -1.0e9f : sv;
        sacc[i][j][r] = sv;
        rm[i][r] = fmaxf(rm[i][r], sv);
      }
  }
  #pragma unroll
  for (int d = 1; d < 16; d <<= 1)
    #pragma unroll
    for (int i = 0; i < 2; ++i)
      #pragma unroll
      for (int r = 0; r < 4; ++r)
        rm[i][r] = fmaxf(rm[i][r], __shfl_xor(rm[i][r], d, 64));

  if (l15 == 0) {
    #pragma unroll
    for (int i = 0; i < 2; ++i)
      #pragma unroll
      for (int r = 0; r < 4; ++r)
        redbuf[0][i * 16 + lhi * 4 + r][wid] = rm[i][r];
  }
  __syncthreads();
  #pragma unroll
  for (int i = 0; i < 2; ++i)
    #pragma unroll
    for (int r = 0; r < 4; ++r) {
      int row = i * 16 + lhi * 4 + r;
      rm[i][r] = fmaxf(fmaxf(redbuf[0][row][0], redbuf[0][row][1]),
                       fmaxf(redbuf[0][row][2], redbuf[0][row][3]));
      sm[i][r] = 0.0f;
    }
  #pragma unroll
  for (int j = 0; j < 8; ++j)
    #pragma unroll
    for (int i = 0; i < 2; ++i)
      #pragma unroll
      for (int r = 0; r < 4; ++r) {
        float pv = __expf(sacc[i][j][r] - rm[i][r]);
        sacc[i][j][r] = pv;
        sm[i][r] += pv;
      }
  #pragma unroll
  for (int d = 1; d < 16; d <<= 1)
    #pragma unroll
    for (int i = 0; i < 2; ++i)
      #pragma unroll
      for (int r = 0; r < 4; ++r)
        sm[i][r] += __shfl_xor(sm[i][r], d, 64);
  if (l15 == 0) {
    #pragma unroll
    for (int i = 0; i < 2; ++i)
      #pragma unroll
      for (int r = 0; r < 4; ++r)
        redbuf[1][i * 16 + lhi * 4 + r][wid] = sm[i][r];
  }
  __syncthreads();
  #pragma unroll
  for (int i = 0; i < 2; ++i)
    #pragma unroll
    for (int r = 0; r < 4; ++r) {
      int row = i * 16 + lhi * 4 + r;
      float tot = redbuf[1][row][0] + redbuf[1][row][1] + redbuf[1][row][2] + redbuf[1][row][3];
      gi[i][r] = 1.0f / tot;
    }

  float* wrow = wout + ((size_t)((b * 8 + h) * 512 + m0)) * 512;
  #pragma unroll
  for (int j = 0; j < 8; ++j)
    #pragma unroll
    for (int i = 0; i < 2; ++i)
      #pragma unroll
      for (int r = 0; r < 4; ++r) {
        float wv = sacc[i][j][r] * gi[i][r];
        int row = i * 16 + lhi * 4 + r;
        int col = c0 + j * 16 + l15;
        Wl[row][col] = f2bf(wv);
        __builtin_nontemporal_store(wv, &wrow[(size_t)row * 512 + col]);
      }
  __syncthreads();

  f32x4 cacc[2];
  #pragma unroll
  for (int i = 0; i < 2; ++i)
    #pragma unroll
    for (int r = 0; r < 4; ++r) cacc[i][r] = 0.0f;
  const u16* vbase = Vt + ((size_t)((b * 8 + h) * 64 + wid * 16 + l15)) * 512;
  #pragma unroll
  for (int kk = 0; kk < 16; ++kk) {
    s16x8 vf = *(const s16x8*)(vbase + kk * 32 + lhi * 8);
    #pragma unroll
    for (int i = 0; i < 2; ++i) {
      s16x8 wf = *(const s16x8*)&Wl[i * 16 + l15][kk * 32 + lhi * 8];
      cacc[i] = mfma16(wf, vf, cacc[i]);
    }
  }

  __syncthreads();                       // all PV reads of Wl done
  u16* ct = &Wl[0][0];                   // [32][72] overlay
  #pragma unroll
  for (int i = 0; i < 2; ++i)
    #pragma unroll
    for (int r = 0; r < 4; ++r)
      ct[(i * 16 + lhi * 4 + r) * 72 + wid * 16 + l15] = f2bf(cacc[i][r]);
  __syncthreads();
  {
    int row = tid >> 3, col = (tid & 7) * 8;
    s16x8 v = *(const s16x8*)&ct[row * 72 + col];
    *(s16x8*)&ctxb[(size_t)(b * 512 + m0 + row) * 512 + h * 64 + col] = v;
  }
  }  // rep loop
}

// ---------------- host ----------------
extern "C" void kernel_launch(void* const* d_in, const int* in_sizes, int n_in,
                              void* d_out, int out_size, void* d_ws, size_t ws_size,
                              hipStream_t stream) {
  const int*   tok = (const int*)d_in[0];
  const float* emb = (const float*)d_in[1];
  const float* Wq  = (const float*)d_in[2];
  const float* bq  = (const float*)d_in[3];
  const float* Wk  = (const float*)d_in[4];
  const float* bk  = (const float*)d_in[5];
  const float* Wv  = (const float*)d_in[6];
  const float* bv  = (const float*)d_in[7];
  const float* Wo  = (const float*)d_in[8];
  const float* bo  = (const float*)d_in[9];
  const float* g1  = (const float*)d_in[10];
  const float* b1  = (const float*)d_in[11];
  const float* Wc1 = (const float*)d_in[12];
  const float* bc1 = (const float*)d_in[13];
  const float* Wc2 = (const float*)d_in[14];
  const float* bc2 = (const float*)d_in[15];
  const float* g2  = (const float*)d_in[16];
  const float* b2  = (const float*)d_in[17];
  (void)in_sizes; (void)n_in; (void)out_size; (void)ws_size;

  float* out_x = (float*)d_out;
  float* out_w = out_x + (size_t)16 * 512 * 512;

  char* p = (char*)d_ws;
  size_t off = 0;
  auto alloc = [&](size_t bytes) { char* r = p + off; off += (bytes + 255) & ~(size_t)255; return r; };
  u16*   xb  = (u16*)alloc((size_t)8192 * 512 * 2);
  u16*   pwo = (u16*)alloc((size_t)8192 * 512 * 2);        // bf16 pre-LN buffer
  char*  regA = alloc((size_t)8192 * 1536 * 2 + (size_t)8192 * 512 * 2);  // QKVb + Vtb; hb overlays
  u16* QKVb = (u16*)regA;                                  // [8192][1536] (V cols unused)
  u16* Vtb  = QKVb + (size_t)8192 * 1536;                  // [B*H][64][512]
  u16* hb   = (u16*)regA;                                  // [8192][2048] overlays (dead QKV/Vt)
  u16* ctxb = (u16*)alloc((size_t)8192 * 512 * 2);
  u16* Wqkvb = (u16*)alloc((size_t)6 * 1536 * 512 * 2);
  u16* Wob   = (u16*)alloc((size_t)6 * 512 * 512 * 2);
  u16* Wc1b  = (u16*)alloc((size_t)6 * 2048 * 512 * 2);
  u16* Wc2b  = (u16*)alloc((size_t)6 * 2048 * 512 * 2);
  float* bqkvb = (float*)alloc((size_t)6 * 1536 * 4);

  prep_kern<<<2048, 256, 0, stream>>>(Wq, Wk, Wv, Wo, Wc1, Wc2, bq, bk, bv, tok, emb,
                                      Wqkvb, Wob, Wc1b, Wc2b, bqkvb, xb);

  const int AREPS = 3;   // DIAGNOSTIC: dur_delta vs R13 = 2 x attn_total
  for (int l = 0; l < 6; ++l) {
    const u16* wqkv_l = Wqkvb + (size_t)l * 1536 * 512;
    const u16* wo_l = Wob + (size_t)l * 512 * 512;
    const u16* w1_l = Wc1b + (size_t)l * 2048 * 512;
    const u16* w2_l = Wc2b + (size_t)l * 2048 * 512;

    gemm_bs<32, false, true><<<768, 256, 0, stream>>>(xb, wqkv_l, bqkvb + l * 1536,
                                                      QKVb, Vtb, 1536, 512, 12);
    attn_kern<<<2048, 256, 0, stream>>>(QKVb, Vtb, tok,
                                        out_w + (size_t)l * 8 * 16 * 512 * 512, ctxb, AREPS);
    gemm_bs<16, false, false><<<512, 256, 0, stream>>>(ctxb, wo_l, bo + l * 512,
                                                       pwo, nullptr, 512, 512, 4);
    ln2_kern<<<2048, 256, 0, stream>>>(pwo, xb, g1 + l * 512, b1 + l * 512, nullptr, xb);
    gemm_bs<32, true, false><<<1024, 256, 0, stream>>>(xb, w1_l, bc1 + l * 2048,
                                                       hb, nullptr, 2048, 512, 16);
    gemm_bs<16, false, false><<<512, 256, 0, stream>>>(hb, w2_l, bc2 + l * 512,
                                                       pwo, nullptr, 512, 2048, 4);
    ln2_kern<<<2048, 256, 0, stream>>>(pwo, xb, g2 + l * 512, b2 + l * 512,
                                       (l == 5 ? out_x : nullptr), xb);
  }
}

// Round 15
// 1035.910 us; speedup vs baseline: 2.2466x; 2.2466x over previous
//
#include <hip/hip_runtime.h>

typedef unsigned short u16;
typedef __attribute__((ext_vector_type(8))) short s16x8;
typedef __attribute__((ext_vector_type(4))) float f32x4;
typedef __attribute__((ext_vector_type(4))) unsigned short u16x4;

#define DEVI __device__ __forceinline__

DEVI float bf2f(u16 h) { union { unsigned u; float f; } v; v.u = ((unsigned)h) << 16; return v.f; }
DEVI u16 f2bf(float f) {
  union { unsigned u; float f; } v; v.f = f;
  unsigned u = v.u;
  unsigned r = (u + 0x7fffu + ((u >> 16) & 1u)) >> 16;
  return (u16)r;
}

DEVI f32x4 mfma16(s16x8 a, s16x8 b, f32x4 c) {
  return __builtin_amdgcn_mfma_f32_16x16x32_bf16(a, b, c, 0, 0, 0);
}

// ---------------- fused setup: weight repack/cvt + QKV bias + embedding ----------------
DEVI void cvt8(const float* __restrict__ in, u16* __restrict__ out, int i) {
  const f32x4* p = (const f32x4*)(in + (size_t)i * 8);
  f32x4 a = p[0], b = p[1];
  u16x4 o0 = { f2bf(a[0]), f2bf(a[1]), f2bf(a[2]), f2bf(a[3]) };
  u16x4 o1 = { f2bf(b[0]), f2bf(b[1]), f2bf(b[2]), f2bf(b[3]) };
  u16x4* q = (u16x4*)(out + (size_t)i * 8);
  q[0] = o0; q[1] = o1;
}

__global__ void prep_kern(const float* __restrict__ Wq, const float* __restrict__ Wk,
                          const float* __restrict__ Wv, const float* __restrict__ Wo,
                          const float* __restrict__ Wc1, const float* __restrict__ Wc2,
                          const float* __restrict__ bq, const float* __restrict__ bk,
                          const float* __restrict__ bv,
                          const int* __restrict__ tok, const float* __restrict__ emb,
                          u16* __restrict__ Wqkvb, u16* __restrict__ Wob,
                          u16* __restrict__ Wc1b, u16* __restrict__ Wc2b,
                          float* __restrict__ bqkvb, u16* __restrict__ xb) {
  const int Rqkv = 6 * 1536 * 512 / 8;   // 589824
  const int Rwo  = 6 * 512 * 512 / 8;    // 196608
  const int Rw1  = 6 * 2048 * 512 / 8;   // 786432
  const int Rw2  = Rw1;
  const int Rb   = 6 * 1536 / 8;         // 1152
  const int Remb = 8192 * 128;           // 1048576 (4 dims each)
  const int total = Rqkv + Rwo + Rw1 + Rw2 + Rb + Remb;
  for (int idx = blockIdx.x * blockDim.x + threadIdx.x; idx < total;
       idx += gridDim.x * blockDim.x) {
    int i = idx;
    if (i < Rqkv) {
      int c8 = i & 63;
      int t = i >> 6;                    // l*1536 + r
      int r = t % 1536, l = t / 1536;
      const float* src; int rr = r;
      if (r < 512) src = Wq;
      else if (r < 1024) { src = Wk; rr = r - 512; }
      else { src = Wv; rr = r - 1024; }
      const f32x4* p = (const f32x4*)(src + ((size_t)(l * 512 + rr) * 512) + c8 * 8);
      f32x4 a = p[0], b = p[1];
      u16x4 o0 = { f2bf(a[0]), f2bf(a[1]), f2bf(a[2]), f2bf(a[3]) };
      u16x4 o1 = { f2bf(b[0]), f2bf(b[1]), f2bf(b[2]), f2bf(b[3]) };
      u16x4* q = (u16x4*)(Wqkvb + (size_t)i * 8);
      q[0] = o0; q[1] = o1;
      continue;
    }
    i -= Rqkv;
    if (i < Rwo) { cvt8(Wo, Wob, i); continue; }
    i -= Rwo;
    if (i < Rw1) { cvt8(Wc1, Wc1b, i); continue; }
    i -= Rw1;
    if (i < Rw2) { cvt8(Wc2, Wc2b, i); continue; }
    i -= Rw2;
    if (i < Rb) {
      #pragma unroll
      for (int u = 0; u < 8; ++u) {
        int j = i * 8 + u;
        int l = j / 1536, r = j % 1536;
        float v = (r < 512) ? bq[l * 512 + r]
                : (r < 1024) ? bk[l * 512 + r - 512] : bv[l * 512 + r - 1024];
        bqkvb[j] = v;
      }
      continue;
    }
    i -= Rb;
    // embedding + pos enc: item i -> (bs, 4-dim chunk)
    {
      int bs = i >> 7;
      int t = i & 127;
      int s = bs & 511;
      int id = tok[bs];
      float pos = (float)(s + 1);
      int j0 = t * 4;
      f32x4 e = *(const f32x4*)(emb + (size_t)id * 512 + j0);
      u16x4 ob;
      #pragma unroll
      for (int u = 0; u < 4; ++u) {
        int j = j0 + u;
        float expo = (float)(j & ~1) * (1.0f / 512.0f);
        float ang = pos / powf(10000.0f, expo);
        float pe = (j & 1) ? cosf(ang) : sinf(ang);
        ob[u] = f2bf(e[u] + pe);
      }
      *(u16x4*)(xb + (size_t)bs * 512 + j0) = ob;
    }
  }
}

// ---------------- B-stationary MFMA GEMM: C = A[M,K] * Bt[N,K]^T ----------------
template <int WM, bool RELU, bool VT>
__global__ __launch_bounds__(256, 2) void gemm_bs(const u16* __restrict__ A,
                                                  const u16* __restrict__ Bt,
                                                  const float* __restrict__ bias,
                                                  u16* __restrict__ Cb, u16* __restrict__ Vt,
                                                  int N, int K, int nN) {
  constexpr int MF = WM / 16;         // m-frags per wave
  constexpr int RPB = WM * 4;         // rows per block
  __shared__ __align__(16) u16 Bsw[128 * 256];   // 64 KB swizzled panel

  const int chunkw = gridDim.x >> 3;
  const int wgid = (blockIdx.x & 7) * chunkw + (blockIdx.x >> 3);
  const int n = wgid % nN, m = wgid / nN;
  const int bn0 = n * 128, bm0 = m * RPB;

  const int tid = threadIdx.x, lane = tid & 63, wid = tid >> 6;
  const int l15 = lane & 15, lhi = lane >> 4;
  const int mrow0 = bm0 + wid * WM;

  f32x4 acc[MF][8];
  #pragma unroll
  for (int i = 0; i < MF; ++i)
    #pragma unroll
    for (int j = 0; j < 8; ++j)
      #pragma unroll
      for (int r = 0; r < 4; ++r) acc[i][j][r] = 0.0f;

  const u16* aB[MF];
  #pragma unroll
  for (int i = 0; i < MF; ++i)
    aB[i] = A + (size_t)(mrow0 + i * 16 + l15) * K + lhi * 8;

  const int rounds = K >> 8;            // K / 256
  for (int r = 0; r < rounds; ++r) {
    const int kb = r << 8;
    s16x8 tmp[16];
    #pragma unroll
    for (int c = 0; c < 16; ++c) {
      int cc = c * 256 + tid;           // chunk 0..4095 (16B each)
      int row = cc >> 5, col = cc & 31;
      tmp[c] = *(const s16x8*)(Bt + (size_t)(bn0 + row) * K + kb + col * 8);
    }
    __syncthreads();                    // previous panel fully consumed
    #pragma unroll
    for (int c = 0; c < 16; ++c) {
      int cc = c * 256 + tid;
      int row = cc >> 5, col = cc & 31;
      int byte = row * 512 + ((col * 16) ^ ((row & 7) << 4));
      *(s16x8*)((char*)Bsw + byte) = tmp[c];
    }
    __syncthreads();                    // panel ready
    #pragma unroll
    for (int ks = 0; ks < 8; ++ks) {
      s16x8 af[MF], bf[8];
      #pragma unroll
      for (int i = 0; i < MF; ++i)
        af[i] = *(const s16x8*)(aB[i] + kb + ks * 32);
      #pragma unroll
      for (int j = 0; j < 8; ++j) {
        int row = j * 16 + l15;
        int byte = row * 512 + (((ks * 64) + lhi * 16) ^ ((row & 7) << 4));
        bf[j] = *(const s16x8*)((char*)Bsw + byte);
      }
      #pragma unroll
      for (int i = 0; i < MF; ++i)
        #pragma unroll
        for (int j = 0; j < 8; ++j)
          acc[i][j] = mfma16(af[i], bf[j], acc[i][j]);
    }
  }

  const int r0 = mrow0 + lhi * 4;
  const int c0 = bn0 + l15;
  if (VT && bn0 >= 1024) {
    // V columns: repack tile via LDS (Bsw dead) -> transposed coalesced stores
    __syncthreads();                    // all B-frag reads of Bsw done
    u16* T = Bsw;                       // [128 s][136] overlay
    #pragma unroll
    for (int i = 0; i < MF; ++i)
      #pragma unroll
      for (int j = 0; j < 8; ++j) {
        int col = c0 + j * 16;
        float bv = bias[col];
        int lr0 = wid * WM + i * 16 + lhi * 4;      // local s row
        int lc = j * 16 + l15;                      // local d col
        #pragma unroll
        for (int r = 0; r < 4; ++r)
          T[(lr0 + r) * 136 + lc] = f2bf(acc[i][j][r] + bv);
      }
    __syncthreads();
    const int b = bm0 >> 9, s0 = bm0 & 511;
    for (int c = tid; c < 2048; c += 256) {
      int dr = c >> 4;                  // local d col 0..127
      int ch = c & 15;                  // 16 chunks of 8 s
      s16x8 v;
      #pragma unroll
      for (int k = 0; k < 8; ++k) v[k] = T[(ch * 8 + k) * 136 + dr];
      int hc = bn0 - 1024 + dr;
      int h = hc >> 6, d = hc & 63;
      *(s16x8*)&Vt[((size_t)((b * 8 + h) * 64 + d)) * 512 + s0 + ch * 8] = v;
    }
  } else {
    #pragma unroll
    for (int i = 0; i < MF; ++i)
      #pragma unroll
      for (int j = 0; j < 8; ++j) {
        int col = c0 + j * 16;
        float bv = bias[col];
        #pragma unroll
        for (int r = 0; r < 4; ++r) {
          int row = r0 + i * 16 + r;
          float v = acc[i][j][r] + bv;
          if (RELU) v = fmaxf(v, 0.0f);
          Cb[(size_t)row * N + col] = f2bf(v);
        }
      }
  }
}

// ---------------- LN over 512: bf16 pre-act + bf16 resid; writes bf16 (+f32 opt) ----------------
__global__ void ln2_kern(const u16* __restrict__ parts,
                         const u16* __restrict__ resid,
                         const float* __restrict__ gam, const float* __restrict__ bet,
                         float* __restrict__ outf, u16* __restrict__ outb) {
  int row = blockIdx.x * 4 + (threadIdx.x >> 6);
  int t = threadIdx.x & 63;
  size_t base = (size_t)row * 512;
  const u16x4* pp = (const u16x4*)(parts + base);
  u16x4 pa = pp[t], pb4 = pp[t + 64];
  const u16x4* rp = (const u16x4*)(resid + base);
  u16x4 ra = rp[t], rb = rp[t + 64];
  f32x4 v0, v1;
  #pragma unroll
  for (int u = 0; u < 4; ++u) {
    v0[u] = bf2f(pa[u]) + bf2f(ra[u]);
    v1[u] = bf2f(pb4[u]) + bf2f(rb[u]);
  }

  float s = v0[0] + v0[1] + v0[2] + v0[3] + v1[0] + v1[1] + v1[2] + v1[3];
  float q = v0[0]*v0[0] + v0[1]*v0[1] + v0[2]*v0[2] + v0[3]*v0[3]
          + v1[0]*v1[0] + v1[1]*v1[1] + v1[2]*v1[2] + v1[3]*v1[3];
  #pragma unroll
  for (int d = 1; d < 64; d <<= 1) { s += __shfl_xor(s, d, 64); q += __shfl_xor(q, d, 64); }
  float mu = s * (1.0f / 512.0f);
  float var = q * (1.0f / 512.0f) - mu * mu;
  float rs = rsqrtf(var + 1e-5f);
  const f32x4* gp = (const f32x4*)gam;
  const f32x4* bp = (const f32x4*)bet;
  f32x4 ga = gp[t], gb = gp[t + 64], ba = bp[t], bb = bp[t + 64];
  f32x4 o0, o1; u16x4 ob0, ob1;
  #pragma unroll
  for (int u = 0; u < 4; ++u) {
    float a0 = (v0[u] - mu) * rs * ga[u] + ba[u];
    float a1 = (v1[u] - mu) * rs * gb[u] + bb[u];
    o0[u] = a0; o1[u] = a1; ob0[u] = f2bf(a0); ob1[u] = f2bf(a1);
  }
  u16x4* obp = (u16x4*)(outb + base);
  obp[t] = ob0; obp[t + 64] = ob1;
  if (outf) {
    f32x4* op = (f32x4*)(outf + base);
    op[t] = o0; op[t + 64] = o1;
  }
}

// ---------------- fused attention: scores MFMA -> mask -> softmax -> w out + ctx MFMA ----------------
__global__ void attn_kern(const u16* __restrict__ QKV, const u16* __restrict__ Vt,
                          const int* __restrict__ tok,
                          float* __restrict__ wout, u16* __restrict__ ctxb) {
  // bijective XCD chunking (grid=2048): one XCD gets all 16 qt of 16 (b,h) groups
  int wg = (blockIdx.x & 7) * 256 + (blockIdx.x >> 3);
  int qt = wg & 15;          // 16 q-tiles of 32 rows
  int h = (wg >> 4) & 7;
  int b = wg >> 7;
  int tid = threadIdx.x;
  int lane = tid & 63, wid = tid >> 6;
  int l15 = lane & 15, lhi = lane >> 4;
  int m0 = qt * 32;

  __shared__ __align__(16) u16 Wl[32][528];
  __shared__ float pmask[512];
  __shared__ float redbuf[2][32][4];

  for (int c = tid; c < 512; c += 256)
    pmask[c] = (tok[b * 512 + c] == 0) ? 1.0f : 0.0f;

  s16x8 qf[2][2];
  const u16* qbase = QKV + (size_t)(b * 512 + m0) * 1536 + h * 64;
  #pragma unroll
  for (int i = 0; i < 2; ++i)
    #pragma unroll
    for (int kk = 0; kk < 2; ++kk)
      qf[i][kk] = *(const s16x8*)(qbase + (size_t)(i * 16 + l15) * 1536 + kk * 32 + lhi * 8);

  f32x4 sacc[2][8];
  #pragma unroll
  for (int i = 0; i < 2; ++i)
    #pragma unroll
    for (int j = 0; j < 8; ++j)
      #pragma unroll
      for (int r = 0; r < 4; ++r) sacc[i][j][r] = 0.0f;

  int c0 = wid * 128;
  const u16* kbase = QKV + (size_t)(b * 512 + c0) * 1536 + 512 + h * 64;
  #pragma unroll
  for (int j = 0; j < 8; ++j) {
    #pragma unroll
    for (int kk = 0; kk < 2; ++kk) {
      s16x8 kf = *(const s16x8*)(kbase + (size_t)(j * 16 + l15) * 1536 + kk * 32 + lhi * 8);
      sacc[0][j] = mfma16(qf[0][kk], kf, sacc[0][j]);
      sacc[1][j] = mfma16(qf[1][kk], kf, sacc[1][j]);
    }
  }
  __syncthreads();  // pmask staged

  float rm[2][4], sm[2][4], gi[2][4];
  #pragma unroll
  for (int i = 0; i < 2; ++i)
    #pragma unroll
    for (int r = 0; r < 4; ++r) rm[i][r] = -3.0e38f;

  #pragma unroll
  for (int j = 0; j < 8; ++j) {
    float pm = pmask[c0 + j * 16 + l15];
    #pragma unroll
    for (int i = 0; i < 2; ++i)
      #pragma unroll
      for (int r = 0; r < 4; ++r) {
        float sv = sacc[i][j][r] * 0.125f;
        sv = (pm != 0.0f) ? -1.0e9f : sv;
        sacc[i][j][r] = sv;
        rm[i][r] = fmaxf(rm[i][r], sv);
      }
  }
  #pragma unroll
  for (int d = 1; d < 16; d <<= 1)
    #pragma unroll
    for (int i = 0; i < 2; ++i)
      #pragma unroll
      for (int r = 0; r < 4; ++r)
        rm[i][r] = fmaxf(rm[i][r], __shfl_xor(rm[i][r], d, 64));

  if (l15 == 0) {
    #pragma unroll
    for (int i = 0; i < 2; ++i)
      #pragma unroll
      for (int r = 0; r < 4; ++r)
        redbuf[0][i * 16 + lhi * 4 + r][wid] = rm[i][r];
  }
  __syncthreads();
  #pragma unroll
  for (int i = 0; i < 2; ++i)
    #pragma unroll
    for (int r = 0; r < 4; ++r) {
      int row = i * 16 + lhi * 4 + r;
      rm[i][r] = fmaxf(fmaxf(redbuf[0][row][0], redbuf[0][row][1]),
                       fmaxf(redbuf[0][row][2], redbuf[0][row][3]));
      sm[i][r] = 0.0f;
    }
  #pragma unroll
  for (int j = 0; j < 8; ++j)
    #pragma unroll
    for (int i = 0; i < 2; ++i)
      #pragma unroll
      for (int r = 0; r < 4; ++r) {
        float pv = __expf(sacc[i][j][r] - rm[i][r]);
        sacc[i][j][r] = pv;
        sm[i][r] += pv;
      }
  #pragma unroll
  for (int d = 1; d < 16; d <<= 1)
    #pragma unroll
    for (int i = 0; i < 2; ++i)
      #pragma unroll
      for (int r = 0; r < 4; ++r)
        sm[i][r] += __shfl_xor(sm[i][r], d, 64);
  if (l15 == 0) {
    #pragma unroll
    for (int i = 0; i < 2; ++i)
      #pragma unroll
      for (int r = 0; r < 4; ++r)
        redbuf[1][i * 16 + lhi * 4 + r][wid] = sm[i][r];
  }
  __syncthreads();
  #pragma unroll
  for (int i = 0; i < 2; ++i)
    #pragma unroll
    for (int r = 0; r < 4; ++r) {
      int row = i * 16 + lhi * 4 + r;
      float tot = redbuf[1][row][0] + redbuf[1][row][1] + redbuf[1][row][2] + redbuf[1][row][3];
      gi[i][r] = 1.0f / tot;
    }

  // normalized weights: bf16 -> LDS (for PV), f32 -> global (regular stores: L2
  // write-combines the 64B segments into full lines and drains lazily under the
  // following GEMM; nontemporal bypassed L2 and forced small serial HBM bursts)
  float* wrow = wout + ((size_t)((b * 8 + h) * 512 + m0)) * 512;
  #pragma unroll
  for (int j = 0; j < 8; ++j)
    #pragma unroll
    for (int i = 0; i < 2; ++i)
      #pragma unroll
      for (int r = 0; r < 4; ++r) {
        float wv = sacc[i][j][r] * gi[i][r];
        int row = i * 16 + lhi * 4 + r;
        int col = c0 + j * 16 + l15;
        Wl[row][col] = f2bf(wv);
        wrow[(size_t)row * 512 + col] = wv;
      }
  __syncthreads();

  // ctx = w * V ; wave wid owns dims [wid*16, wid*16+16)
  f32x4 cacc[2];
  #pragma unroll
  for (int i = 0; i < 2; ++i)
    #pragma unroll
    for (int r = 0; r < 4; ++r) cacc[i][r] = 0.0f;
  const u16* vbase = Vt + ((size_t)((b * 8 + h) * 64 + wid * 16 + l15)) * 512;
  #pragma unroll
  for (int kk = 0; kk < 16; ++kk) {
    s16x8 vf = *(const s16x8*)(vbase + kk * 32 + lhi * 8);
    #pragma unroll
    for (int i = 0; i < 2; ++i) {
      s16x8 wf = *(const s16x8*)&Wl[i * 16 + l15][kk * 32 + lhi * 8];
      cacc[i] = mfma16(wf, vf, cacc[i]);
    }
  }

  // ctx store: repack via LDS (reuse Wl region) -> 16B coalesced stores
  __syncthreads();                       // all PV reads of Wl done
  u16* ct = &Wl[0][0];                   // [32][72] overlay
  #pragma unroll
  for (int i = 0; i < 2; ++i)
    #pragma unroll
    for (int r = 0; r < 4; ++r)
      ct[(i * 16 + lhi * 4 + r) * 72 + wid * 16 + l15] = f2bf(cacc[i][r]);
  __syncthreads();
  {
    int row = tid >> 3, col = (tid & 7) * 8;
    s16x8 v = *(const s16x8*)&ct[row * 72 + col];
    *(s16x8*)&ctxb[(size_t)(b * 512 + m0 + row) * 512 + h * 64 + col] = v;
  }
}

// ---------------- host ----------------
extern "C" void kernel_launch(void* const* d_in, const int* in_sizes, int n_in,
                              void* d_out, int out_size, void* d_ws, size_t ws_size,
                              hipStream_t stream) {
  const int*   tok = (const int*)d_in[0];
  const float* emb = (const float*)d_in[1];
  const float* Wq  = (const float*)d_in[2];
  const float* bq  = (const float*)d_in[3];
  const float* Wk  = (const float*)d_in[4];
  const float* bk  = (const float*)d_in[5];
  const float* Wv  = (const float*)d_in[6];
  const float* bv  = (const float*)d_in[7];
  const float* Wo  = (const float*)d_in[8];
  const float* bo  = (const float*)d_in[9];
  const float* g1  = (const float*)d_in[10];
  const float* b1  = (const float*)d_in[11];
  const float* Wc1 = (const float*)d_in[12];
  const float* bc1 = (const float*)d_in[13];
  const float* Wc2 = (const float*)d_in[14];
  const float* bc2 = (const float*)d_in[15];
  const float* g2  = (const float*)d_in[16];
  const float* b2  = (const float*)d_in[17];
  (void)in_sizes; (void)n_in; (void)out_size; (void)ws_size;

  float* out_x = (float*)d_out;
  float* out_w = out_x + (size_t)16 * 512 * 512;

  char* p = (char*)d_ws;
  size_t off = 0;
  auto alloc = [&](size_t bytes) { char* r = p + off; off += (bytes + 255) & ~(size_t)255; return r; };
  u16*   xb  = (u16*)alloc((size_t)8192 * 512 * 2);
  u16*   pwo = (u16*)alloc((size_t)8192 * 512 * 2);        // bf16 pre-LN buffer
  char*  regA = alloc((size_t)8192 * 1536 * 2 + (size_t)8192 * 512 * 2);  // QKVb + Vtb; hb overlays
  u16* QKVb = (u16*)regA;                                  // [8192][1536] (V cols unused)
  u16* Vtb  = QKVb + (size_t)8192 * 1536;                  // [B*H][64][512]
  u16* hb   = (u16*)regA;                                  // [8192][2048] overlays (dead QKV/Vt)
  u16* ctxb = (u16*)alloc((size_t)8192 * 512 * 2);
  u16* Wqkvb = (u16*)alloc((size_t)6 * 1536 * 512 * 2);
  u16* Wob   = (u16*)alloc((size_t)6 * 512 * 512 * 2);
  u16* Wc1b  = (u16*)alloc((size_t)6 * 2048 * 512 * 2);
  u16* Wc2b  = (u16*)alloc((size_t)6 * 2048 * 512 * 2);
  float* bqkvb = (float*)alloc((size_t)6 * 1536 * 4);

  prep_kern<<<2048, 256, 0, stream>>>(Wq, Wk, Wv, Wo, Wc1, Wc2, bq, bk, bv, tok, emb,
                                      Wqkvb, Wob, Wc1b, Wc2b, bqkvb, xb);

  for (int l = 0; l < 6; ++l) {
    const u16* wqkv_l = Wqkvb + (size_t)l * 1536 * 512;
    const u16* wo_l = Wob + (size_t)l * 512 * 512;
    const u16* w1_l = Wc1b + (size_t)l * 2048 * 512;
    const u16* w2_l = Wc2b + (size_t)l * 2048 * 512;

    gemm_bs<32, false, true><<<768, 256, 0, stream>>>(xb, wqkv_l, bqkvb + l * 1536,
                                                      QKVb, Vtb, 1536, 512, 12);
    attn_kern<<<2048, 256, 0, stream>>>(QKVb, Vtb, tok,
                                        out_w + (size_t)l * 8 * 16 * 512 * 512, ctxb);
    gemm_bs<16, false, false><<<512, 256, 0, stream>>>(ctxb, wo_l, bo + l * 512,
                                                       pwo, nullptr, 512, 512, 4);
    ln2_kern<<<2048, 256, 0, stream>>>(pwo, xb, g1 + l * 512, b1 + l * 512, nullptr, xb);
    gemm_bs<32, true, false><<<1024, 256, 0, stream>>>(xb, w1_l, bc1 + l * 2048,
                                                       hb, nullptr, 2048, 512, 16);
    gemm_bs<16, false, false><<<512, 256, 0, stream>>>(hb, w2_l, bc2 + l * 512,
                                                       pwo, nullptr, 512, 2048, 4);
    ln2_kern<<<2048, 256, 0, stream>>>(pwo, xb, g2 + l * 512, b2 + l * 512,
                                       (l == 5 ? out_x : nullptr), xb);
  }
}